// Round 1
// baseline (193.502 us; speedup 1.0000x reference)
//
#include <hip/hip_runtime.h>

#define IN_F   4096
#define OUT_F  4096
#define BATCH  512
#define NCONN  64

// ---------------- Kernel 1: transpose x (B, IN_F) -> xT (IN_F, B) ----------------
__global__ __launch_bounds__(256) void transpose_kernel(const float* __restrict__ x,
                                                        float* __restrict__ xT) {
    __shared__ float tile[32][33];
    const int j0 = blockIdx.x * 32;   // feature dim
    const int b0 = blockIdx.y * 32;   // batch dim
    const int tx = threadIdx.x;       // 0..31
    const int ty = threadIdx.y;       // 0..7
#pragma unroll
    for (int r = 0; r < 32; r += 8)
        tile[ty + r][tx] = x[(size_t)(b0 + ty + r) * IN_F + (j0 + tx)];
    __syncthreads();
#pragma unroll
    for (int r = 0; r < 32; r += 8)
        xT[(size_t)(j0 + ty + r) * BATCH + (b0 + tx)] = tile[tx][ty + r];
}

// ---------------- Kernel 2: per-output-feature gather + reduce ----------------
// One block per output feature o. 128 threads; thread t owns batches [4t, 4t+4).
__global__ __launch_bounds__(128) void agg_kernel(const float* __restrict__ xT,
                                                  const int* __restrict__ conn,
                                                  const int* __restrict__ opidx,
                                                  float* __restrict__ out) {
    const int o   = blockIdx.x;
    const int tid = threadIdx.x;

    __shared__ int cs[NCONN];
    if (tid < NCONN) cs[tid] = conn[o * NCONN + tid];
    __syncthreads();

    const int b0 = tid * 4;

    float4 v = *reinterpret_cast<const float4*>(xT + (size_t)cs[0] * BATCH + b0);
    float4 s = v, mx = v, mn = v;

#pragma unroll 8
    for (int k = 1; k < NCONN; ++k) {
        float4 w = *reinterpret_cast<const float4*>(xT + (size_t)cs[k] * BATCH + b0);
        s.x += w.x;  s.y += w.y;  s.z += w.z;  s.w += w.w;
        mx.x = fmaxf(mx.x, w.x);  mx.y = fmaxf(mx.y, w.y);
        mx.z = fmaxf(mx.z, w.z);  mx.w = fmaxf(mx.w, w.w);
        mn.x = fminf(mn.x, w.x);  mn.y = fminf(mn.y, w.y);
        mn.z = fminf(mn.z, w.z);  mn.w = fminf(mn.w, w.w);
    }

    const int op = opidx[o];

    float* __restrict__ fwd  = out;                              // (B, OUT_F)
    float* __restrict__ outp = out + (size_t)BATCH * OUT_F;      // (B, 4, OUT_F)

    const float sv[4]  = {s.x,  s.y,  s.z,  s.w};
    const float mxv[4] = {mx.x, mx.y, mx.z, mx.w};
    const float mnv[4] = {mn.x, mn.y, mn.z, mn.w};

#pragma unroll
    for (int i = 0; i < 4; ++i) {
        const float ss = sv[i];
        const float mm = ss * 0.015625f;   // /64
        const float hx = mxv[i];
        const float ln = mnv[i];
        const size_t base = (size_t)(b0 + i) * (4 * OUT_F) + o;
        outp[base]             = mm;   // op 0: mean
        outp[base + OUT_F]     = ss;   // op 1: sum
        outp[base + 2 * OUT_F] = hx;   // op 2: max
        outp[base + 3 * OUT_F] = ln;   // op 3: min
        const float sel = (op == 0) ? mm : (op == 1) ? ss : (op == 2) ? hx : ln;
        fwd[(size_t)(b0 + i) * OUT_F + o] = sel;
    }
}

extern "C" void kernel_launch(void* const* d_in, const int* in_sizes, int n_in,
                              void* d_out, int out_size, void* d_ws, size_t ws_size,
                              hipStream_t stream) {
    const float* x     = (const float*)d_in[0];
    const int*   conn  = (const int*)d_in[1];
    const int*   opidx = (const int*)d_in[2];
    float*       out   = (float*)d_out;
    float*       xT    = (float*)d_ws;   // IN_F * BATCH floats = 8 MiB

    dim3 tb(32, 8);
    dim3 tg(IN_F / 32, BATCH / 32);
    transpose_kernel<<<tg, tb, 0, stream>>>(x, xT);
    agg_kernel<<<OUT_F, 128, 0, stream>>>(xT, conn, opidx, out);
}

// Round 2
// 62.433 us; speedup vs baseline: 3.0994x; 3.0994x over previous
//
#include <hip/hip_runtime.h>

#define IN_F   4096
#define OUT_F  4096
#define BATCH  512
#define NCONN  64
#define OT     16     // output features per block
#define BT     128    // batch elements per block
#define NTHR   256

// ---------------- Kernel 1: transpose x (B, IN_F) -> xT (IN_F, B) ----------------
__global__ __launch_bounds__(256) void transpose_kernel(const float* __restrict__ x,
                                                        float* __restrict__ xT) {
    __shared__ float tile[32][33];
    const int j0 = blockIdx.x * 32;   // feature dim
    const int b0 = blockIdx.y * 32;   // batch dim
    const int tx = threadIdx.x;       // 0..31
    const int ty = threadIdx.y;       // 0..7
#pragma unroll
    for (int r = 0; r < 32; r += 8)
        tile[ty + r][tx] = x[(size_t)(b0 + ty + r) * IN_F + (j0 + tx)];
    __syncthreads();
#pragma unroll
    for (int r = 0; r < 32; r += 8)
        xT[(size_t)(j0 + ty + r) * BATCH + (b0 + tx)] = tile[tx][ty + r];
}

// ---------------- Kernel 2: (OT x BT) tile gather + reduce, staged coalesced writes ----
__global__ __launch_bounds__(NTHR) void agg_kernel(const float* __restrict__ xT,
                                                   const int* __restrict__ conn,
                                                   const int* __restrict__ opidx,
                                                   float* __restrict__ out) {
    // grid = (OUT_F/OT) * (BATCH/BT) = 256 * 4 = 1024 blocks.
    // XCD-chunked swizzle: hardware round-robins blockIdx across 8 XCDs;
    // remap so the 4 b-tile siblings of each o-tile (identical gather columns)
    // land on the same XCD -> column fetched once per XCD, not 4x.
    const int nwg = gridDim.x;                     // 1024, divisible by 8
    const int cpx = nwg >> 3;                      // 128
    const int bid = blockIdx.x;
    const int swz = (bid & 7) * cpx + (bid >> 3);  // bijective
    const int ot  = swz >> 2;                      // 0..255
    const int bt  = swz & 3;                       // 0..3
    const int o0  = ot * OT;
    const int b0  = bt * BT;
    const int tid = threadIdx.x;

    __shared__ int   cs[OT][NCONN];        // 4 KB
    __shared__ int   ops[OT];
    __shared__ float stage[4][OT][BT];     // 32 KB: sum, max, min, fwd

    // stage connection rows + op ids
    for (int i = tid; i < OT * NCONN; i += NTHR)
        (&cs[0][0])[i] = conn[o0 * NCONN + i];
    if (tid < OT) ops[tid] = opidx[o0 + tid];
    __syncthreads();

    const int lane = tid & 31;   // 32 lanes cover BT=128 as float4
    const int grp  = tid >> 5;   // 8 groups, each handles 2 o's
    const int bb   = lane * 4;

    const float* __restrict__ xbase = xT + b0 + bb;

#pragma unroll
    for (int oi = 0; oi < OT / 8; ++oi) {
        const int ol = grp * (OT / 8) + oi;
        const int* __restrict__ crow = cs[ol];

        float4 v = *reinterpret_cast<const float4*>(xbase + crow[0] * BATCH);
        float4 s = v, mx = v, mn = v;
#pragma unroll 16
        for (int k = 1; k < NCONN; ++k) {
            float4 w = *reinterpret_cast<const float4*>(xbase + crow[k] * BATCH);
            s.x += w.x;  s.y += w.y;  s.z += w.z;  s.w += w.w;
            mx.x = fmaxf(mx.x, w.x);  mx.y = fmaxf(mx.y, w.y);
            mx.z = fmaxf(mx.z, w.z);  mx.w = fmaxf(mx.w, w.w);
            mn.x = fminf(mn.x, w.x);  mn.y = fminf(mn.y, w.y);
            mn.z = fminf(mn.z, w.z);  mn.w = fminf(mn.w, w.w);
        }

        const int op = ops[ol];
        const float sv[4]  = {s.x,  s.y,  s.z,  s.w};
        const float mxv[4] = {mx.x, mx.y, mx.z, mx.w};
        const float mnv[4] = {mn.x, mn.y, mn.z, mn.w};
#pragma unroll
        for (int i = 0; i < 4; ++i) {
            const float ss = sv[i];
            stage[0][ol][bb + i] = ss;
            stage[1][ol][bb + i] = mxv[i];
            stage[2][ol][bb + i] = mnv[i];
            const float f = (op == 0) ? ss * 0.015625f
                          : (op == 1) ? ss
                          : (op == 2) ? mxv[i] : mnv[i];
            stage[3][ol][bb + i] = f;
        }
    }
    __syncthreads();

    // ---- coalesced write-out: float4 lines along o ----
    float* __restrict__ fwd  = out;                          // (B, OUT_F)
    float* __restrict__ outp = out + (size_t)BATCH * OUT_F;  // (B, 4, OUT_F)

#pragma unroll
    for (int it = 0; it < (OT * BT / 4) / NTHR; ++it) {      // 2 iters
        const int idx = it * NTHR + tid;   // 0..511
        const int b   = idx >> 2;          // 0..127
        const int olb = (idx & 3) * 4;     // 0,4,8,12

        float4 sm = make_float4(stage[0][olb][b], stage[0][olb+1][b],
                                stage[0][olb+2][b], stage[0][olb+3][b]);
        float4 xm = make_float4(stage[1][olb][b], stage[1][olb+1][b],
                                stage[1][olb+2][b], stage[1][olb+3][b]);
        float4 nm = make_float4(stage[2][olb][b], stage[2][olb+1][b],
                                stage[2][olb+2][b], stage[2][olb+3][b]);
        float4 fw = make_float4(stage[3][olb][b], stage[3][olb+1][b],
                                stage[3][olb+2][b], stage[3][olb+3][b]);
        float4 mean = make_float4(sm.x * 0.015625f, sm.y * 0.015625f,
                                  sm.z * 0.015625f, sm.w * 0.015625f);

        const size_t rowF = (size_t)(b0 + b) * OUT_F + o0 + olb;
        const size_t rowO = (size_t)(b0 + b) * (4 * OUT_F) + o0 + olb;
        *reinterpret_cast<float4*>(fwd  + rowF)              = fw;
        *reinterpret_cast<float4*>(outp + rowO)              = mean;
        *reinterpret_cast<float4*>(outp + rowO + OUT_F)      = sm;
        *reinterpret_cast<float4*>(outp + rowO + 2 * OUT_F)  = xm;
        *reinterpret_cast<float4*>(outp + rowO + 3 * OUT_F)  = nm;
    }
}

extern "C" void kernel_launch(void* const* d_in, const int* in_sizes, int n_in,
                              void* d_out, int out_size, void* d_ws, size_t ws_size,
                              hipStream_t stream) {
    const float* x     = (const float*)d_in[0];
    const int*   conn  = (const int*)d_in[1];
    const int*   opidx = (const int*)d_in[2];
    float*       out   = (float*)d_out;
    float*       xT    = (float*)d_ws;   // IN_F * BATCH floats = 8 MiB

    dim3 tb(32, 8);
    dim3 tg(IN_F / 32, BATCH / 32);
    transpose_kernel<<<tg, tb, 0, stream>>>(x, xT);

    const int nblocks = (OUT_F / OT) * (BATCH / BT);  // 1024
    agg_kernel<<<nblocks, NTHR, 0, stream>>>(xT, conn, opidx, out);
}

// Round 4
// 35.776 us; speedup vs baseline: 5.4087x; 1.7451x over previous
//
#include <hip/hip_runtime.h>

#define IN_F   4096
#define OUT_F  4096
#define BATCH  512
#define NCONN  64
#define OT     16     // output features per block
#define BT     128    // batch elements per block
#define NTHR   256

typedef float f4 __attribute__((ext_vector_type(4)));   // native vector for NT stores

// ---------------- Kernel 1: transpose x (B, IN_F) -> xT (IN_F, B) ----------------
// 64x64 tiles, float4 loads AND float4 stores, XOR-swizzled LDS (2-way max).
__global__ __launch_bounds__(256) void transpose_kernel(const float* __restrict__ x,
                                                        float* __restrict__ xT) {
    __shared__ float tile[64 * 68];          // logical [row=b][col=j], swizzled cols
    const int j0 = blockIdx.x * 64;          // feature dim
    const int b0 = blockIdx.y * 64;          // batch dim
    const int t  = threadIdx.x;
    const int c  = t & 15;                   // float4 index within 64
    const int r0 = t >> 4;                   // 0..15

#pragma unroll
    for (int it = 0; it < 4; ++it) {
        const int r  = r0 + it * 16;                        // batch row in tile
        const int pc = (4 * c) ^ (((r >> 2) & 7) << 2);     // swizzled col (16B-aligned)
        const float4 v = *reinterpret_cast<const float4*>(
            x + (size_t)(b0 + r) * IN_F + j0 + 4 * c);
        *reinterpret_cast<float4*>(&tile[r * 68 + pc]) = v;
    }
    __syncthreads();
#pragma unroll
    for (int it = 0; it < 4; ++it) {
        const int jj = r0 + it * 16;                        // feature row of xT
        float4 v;
        float* vv = reinterpret_cast<float*>(&v);
#pragma unroll
        for (int i = 0; i < 4; ++i) {
            const int rr   = 4 * c + i;                     // batch index
            const int pcol = jj ^ (((rr >> 2) & 7) << 2);
            vv[i] = tile[rr * 68 + pcol];
        }
        *reinterpret_cast<float4*>(xT + (size_t)(j0 + jj) * BATCH + b0 + 4 * c) = v;
    }
}

// ---------------- Kernel 2: (OT x BT) tile gather + reduce ----------------
__global__ __launch_bounds__(NTHR) void agg_kernel(const float* __restrict__ xT,
                                                   const int* __restrict__ conn,
                                                   const int* __restrict__ opidx,
                                                   float* __restrict__ out) {
    // grid = 256 o-tiles * 4 b-tiles = 1024 blocks, 4/CU -> fully resident.
    // XCD partition (HW round-robins bid across 8 XCDs): XCD i owns b-tile
    // (i>>1) and o-tiles ((i&1)*128 + 0..127). Per-XCD xT footprint =
    // 4096 cols * 512 B = 2 MB < 4 MB L2 -> gathers become L2 hits.
    const int bid = blockIdx.x;
    const int xcd = bid & 7;
    const int ot  = ((xcd & 1) << 7) | (bid >> 3);   // 0..255
    const int bt  = xcd >> 1;                        // 0..3
    const int o0  = ot * OT;
    const int b0  = bt * BT;
    const int tid = threadIdx.x;

    __shared__ int   cs[OT][NCONN];          // 4 KB
    __shared__ int   ops[OT];
    __shared__ float stage[3][OT][BT + 4];   // ~24.8 KB: sum, max, min

    for (int i = tid; i < OT * NCONN; i += NTHR)
        (&cs[0][0])[i] = conn[o0 * NCONN + i];
    if (tid < OT) ops[tid] = opidx[o0 + tid];
    __syncthreads();

    const int lane = tid & 31;   // 32 lanes cover BT=128 as float4
    const int grp  = tid >> 5;   // 8 groups of 32 threads
    const int bb   = lane * 4;
    const float* __restrict__ xbase = xT + b0 + bb;

    // two independent gather streams per thread (2 o's) for MLP
    const int ol0 = grp * 2;
    const int ol1 = ol0 + 1;
    const int* __restrict__ c0 = cs[ol0];
    const int* __restrict__ c1 = cs[ol1];

    float4 s0 = make_float4(0.f, 0.f, 0.f, 0.f), s1 = s0;
    float4 mx0 = make_float4(-__builtin_inff(), -__builtin_inff(),
                             -__builtin_inff(), -__builtin_inff());
    float4 mx1 = mx0;
    float4 mn0 = make_float4(__builtin_inff(), __builtin_inff(),
                             __builtin_inff(), __builtin_inff());
    float4 mn1 = mn0;

#pragma unroll 8
    for (int k = 0; k < NCONN; ++k) {
        const float4 a = *reinterpret_cast<const float4*>(xbase + c0[k] * BATCH);
        const float4 b = *reinterpret_cast<const float4*>(xbase + c1[k] * BATCH);
        s0.x += a.x;  s0.y += a.y;  s0.z += a.z;  s0.w += a.w;
        mx0.x = fmaxf(mx0.x, a.x); mx0.y = fmaxf(mx0.y, a.y);
        mx0.z = fmaxf(mx0.z, a.z); mx0.w = fmaxf(mx0.w, a.w);
        mn0.x = fminf(mn0.x, a.x); mn0.y = fminf(mn0.y, a.y);
        mn0.z = fminf(mn0.z, a.z); mn0.w = fminf(mn0.w, a.w);
        s1.x += b.x;  s1.y += b.y;  s1.z += b.z;  s1.w += b.w;
        mx1.x = fmaxf(mx1.x, b.x); mx1.y = fmaxf(mx1.y, b.y);
        mx1.z = fmaxf(mx1.z, b.z); mx1.w = fmaxf(mx1.w, b.w);
        mn1.x = fminf(mn1.x, b.x); mn1.y = fminf(mn1.y, b.y);
        mn1.z = fminf(mn1.z, b.z); mn1.w = fminf(mn1.w, b.w);
    }

    *reinterpret_cast<float4*>(&stage[0][ol0][bb]) = s0;
    *reinterpret_cast<float4*>(&stage[1][ol0][bb]) = mx0;
    *reinterpret_cast<float4*>(&stage[2][ol0][bb]) = mn0;
    *reinterpret_cast<float4*>(&stage[0][ol1][bb]) = s1;
    *reinterpret_cast<float4*>(&stage[1][ol1][bb]) = mx1;
    *reinterpret_cast<float4*>(&stage[2][ol1][bb]) = mn1;
    __syncthreads();

    // ---- coalesced nontemporal write-out: float4 lines along o ----
    float* __restrict__ fwd  = out;                          // (B, OUT_F)
    float* __restrict__ outp = out + (size_t)BATCH * OUT_F;  // (B, 4, OUT_F)

#pragma unroll
    for (int it = 0; it < 2; ++it) {
        const int idx = it * NTHR + tid;   // 0..511
        const int b   = idx >> 2;          // 0..127
        const int olb = (idx & 3) * 4;     // 0,4,8,12

        float sm[4], xm[4], nm[4], mean[4], fw[4];
#pragma unroll
        for (int i = 0; i < 4; ++i) {
            sm[i]   = stage[0][olb + i][b];
            xm[i]   = stage[1][olb + i][b];
            nm[i]   = stage[2][olb + i][b];
            mean[i] = sm[i] * 0.015625f;
            const int op = ops[olb + i];
            fw[i] = (op == 0) ? mean[i] : (op == 1) ? sm[i] : (op == 2) ? xm[i] : nm[i];
        }

        const size_t rowF = (size_t)(b0 + b) * OUT_F + o0 + olb;
        const size_t rowO = (size_t)(b0 + b) * (4 * OUT_F) + o0 + olb;
        __builtin_nontemporal_store((f4){fw[0], fw[1], fw[2], fw[3]},
                                    reinterpret_cast<f4*>(fwd + rowF));
        __builtin_nontemporal_store((f4){mean[0], mean[1], mean[2], mean[3]},
                                    reinterpret_cast<f4*>(outp + rowO));
        __builtin_nontemporal_store((f4){sm[0], sm[1], sm[2], sm[3]},
                                    reinterpret_cast<f4*>(outp + rowO + OUT_F));
        __builtin_nontemporal_store((f4){xm[0], xm[1], xm[2], xm[3]},
                                    reinterpret_cast<f4*>(outp + rowO + 2 * OUT_F));
        __builtin_nontemporal_store((f4){nm[0], nm[1], nm[2], nm[3]},
                                    reinterpret_cast<f4*>(outp + rowO + 3 * OUT_F));
    }
}

extern "C" void kernel_launch(void* const* d_in, const int* in_sizes, int n_in,
                              void* d_out, int out_size, void* d_ws, size_t ws_size,
                              hipStream_t stream) {
    const float* x     = (const float*)d_in[0];
    const int*   conn  = (const int*)d_in[1];
    const int*   opidx = (const int*)d_in[2];
    float*       out   = (float*)d_out;
    float*       xT    = (float*)d_ws;   // IN_F * BATCH floats = 8 MiB

    dim3 tg(IN_F / 64, BATCH / 64);      // 64 x 8 = 512 blocks
    transpose_kernel<<<tg, 256, 0, stream>>>(x, xT);

    const int nblocks = (OUT_F / OT) * (BATCH / BT);  // 1024
    agg_kernel<<<nblocks, NTHR, 0, stream>>>(xT, conn, opidx, out);
}